// Round 4
// baseline (11070.544 us; speedup 1.0000x reference)
//
#include <hip/hip_runtime.h>

typedef __attribute__((ext_vector_type(8))) short s16x8;
typedef __attribute__((ext_vector_type(4))) float f32x4;
typedef __attribute__((ext_vector_type(2))) float f32x2;

#define B_ 64
#define T_ 512
#define H_ 1024
#define G4 4096      // 4*H
#define K2 2048      // D + H (fused input+recurrent K)
#define NPERS 256    // persistent grid = 1 block per CU
#define WLDS_BYTES 131072
#define LDS_BYTES (WLDS_BYTES + 64 * 33 * 4)   // weights + gbuf = 139968 B <= 160 KiB
#define HIST_SLICES 514                        // slices of 65536 shorts (128 KB) each

__device__ __forceinline__ short f2bf(float f) {
  union { float f; unsigned u; } x; x.f = f;
  unsigned r = (x.u + 0x7fffu + ((x.u >> 16) & 1u)) >> 16;  // RNE
  return (short)r;
}

__device__ __forceinline__ float fast_sigmoid(float x) {
  return 1.f / (1.f + __expf(-x));
}
__device__ __forceinline__ float fast_tanh(float x) {
  float e = __expf(-2.f * fabsf(x));          // overflow-safe
  float t = (1.f - e) / (1.f + e);
  return copysignf(t, x);
}

// MALL-coherent 16B load as two 8B relaxed agent-scope atomic loads (bypasses the
// non-coherent per-XCD L2). Used only in the non-HIST (address-reusing) mode.
__device__ __forceinline__ s16x8 cohload(const short* p) {
  union { unsigned long long u[2]; s16x8 v; } x;
  unsigned long long* q = (unsigned long long*)p;
  x.u[0] = __hip_atomic_load(q,     __ATOMIC_RELAXED, __HIP_MEMORY_SCOPE_AGENT);
  x.u[1] = __hip_atomic_load(q + 1, __ATOMIC_RELAXED, __HIP_MEMORY_SCOPE_AGENT);
  return x.v;
}

// Prep (one grid-stride kernel, ws re-poisoned 0xAA each call so rebuild everything):
//  Wp   [L][128 nblk][64 iter][2 frag][64 lane][8]  bf16  — exact wave-read order (coalesced B)
//  Xp   [T][128 chunk][64 b][8]                     bf16  — A-fragment chunked layout for x
//  h0/h1 [2 parity][128 chunk][64 b][8]             bf16  — fallback/non-HIST exchange bufs
//  hist0/hist1 [514 slice][128 chunk][64 b][8]      bf16  — HIST mode: never-reused slices
//  c0/c1, bias — only used by the (non-cooperative) fallback path
//  bar  [1024] u32 — hierarchical monotonic barrier: group g at bar[g*32], root at bar[512]
__global__ void prep_kernel(const float* __restrict__ input_, const float* __restrict__ hx,
                            const float* __restrict__ cx, const float* __restrict__ W_ih,
                            const float* __restrict__ W_hh, const float* __restrict__ b_ih,
                            const float* __restrict__ b_hh,
                            short* __restrict__ Wp, float* __restrict__ bias,
                            short* __restrict__ Xp, short* __restrict__ h0buf,
                            short* __restrict__ h1buf, float* __restrict__ c0,
                            float* __restrict__ c1, unsigned* __restrict__ bar,
                            short* __restrict__ hist0, short* __restrict__ hist1,
                            int use_xbf, int use_hist)
{
  const long total = use_xbf ? 33554432L : 16777216L;
  for (long idx = (long)blockIdx.x * blockDim.x + threadIdx.x; idx < total;
       idx += (long)gridDim.x * blockDim.x) {
    if (use_xbf && idx < 33554432L) {
      int e = idx & 7;
      int b = (idx >> 3) & 63;
      long tc = idx >> 9;
      int c = (int)(tc & 127);
      int t = (int)(tc >> 7);
      Xp[idx] = f2bf(input_[((long)b * T_ + t) * H_ + c * 8 + e]);
    }
    if (idx < 16777216L) {
      int lb = (int)(idx >> 16);            // layer*128+nblk
      int layer = lb >> 7, nblk = lb & 127;
      int r = (int)(idx & 65535);
      int e = r & 7;
      int lane = (r >> 3) & 63;
      int fragiter = r >> 9;
      int frag = fragiter & 1, iter = fragiter >> 1;
      int n = frag * 16 + (lane & 15);
      int k = iter * 32 + (lane >> 4) * 8 + e;
      int j = (n >> 3) * H_ + nblk * 8 + (n & 7);   // gate row (i,f,g,o grouped per block)
      float v = (k < H_) ? W_ih[((long)(layer << 12) + j) * H_ + k]
                         : W_hh[((long)(layer << 12) + j) * H_ + (k - H_)];
      Wp[idx] = f2bf(v);
    }
    if (idx < 8192) bias[idx] = b_ih[idx] + b_hh[idx];
    if (idx < 65536) {
      int b = (int)(idx >> 10), n = (int)(idx & 1023);
      int pi = (n >> 3) * 512 + b * 8 + (n & 7);    // chunked layout
      short i0 = f2bf(hx[(b * 2 + 0) * H_ + n]);
      short i1 = f2bf(hx[(b * 2 + 1) * H_ + n]);
      h0buf[65536 + pi] = i0;   // parity-1 initial state (non-HIST / fallback)
      h1buf[65536 + pi] = i1;
      if (use_hist) {
        hist0[pi] = i0;             // slice 0: read by layer0/layer1 at s=0/..
        hist1[65536 + pi] = i1;     // slice 1: read by layer1 at s=1
      }
      c0[pi] = cx[(b * 2 + 0) * H_ + n];
      c1[pi] = cx[(b * 2 + 1) * H_ + n];
    }
    if (idx < 1024) bar[idx] = 0u;
  }
}

// ---- persistent cooperative kernel ----
// 256 blocks (1/CU pinned by 136 KB LDS). Weights in LDS once. c-state + bias in
// registers. HIST mode: h exchanged via never-reused history slices — producers
// write-through to MALL (agent atomic stores), consumers use PLAIN loads (first
// touch per address → L2 miss → MALL fetch is fresh; 16 blocks/XCD then share the
// slice in their XCD L2). One hierarchical monotonic barrier per step.

#define UNR16 _Pragma("unroll") for (int j = 0; j < 16; j++)

#define LQX(R, Q)                                                                \
  do {                                                                           \
    if (layer == 0) {                                                            \
      if (XBF) {                                                                 \
        UNR16 R[j] = *(const s16x8*)(pAxl + ((Q) * 16 + j) * 2048);              \
      } else {                                                                   \
        UNR16 {                                                                  \
          const float* pp = xrow_f + ((Q) * 16 + j) * 32;                        \
          s16x8 tmp;                                                             \
          _Pragma("unroll") for (int e = 0; e < 8; e++) tmp[e] = f2bf(pp[e]);    \
          R[j] = tmp;                                                            \
        }                                                                        \
      }                                                                          \
    } else {                                                                     \
      if (HIST) { UNR16 R[j] = *(const s16x8*)(pAxl + ((Q) * 16 + j) * 2048); }  \
      else      { UNR16 R[j] = cohload(pAxl + ((Q) * 16 + j) * 2048); }          \
    }                                                                            \
  } while (0)

#define LQH(R, Q2)                                                               \
  do {                                                                           \
    if (HIST) { UNR16 R[j] = *(const s16x8*)(pAhl + ((Q2) * 16 + j) * 2048); }   \
    else      { UNR16 R[j] = cohload(pAhl + ((Q2) * 16 + j) * 2048); }           \
  } while (0)

#define COMPQ(R, Q)                                                              \
  do {                                                                           \
    _Pragma("unroll") for (int j = 0; j < 16; j++) {                             \
      const int i_ = (Q) * 16 + j;                                               \
      s16x8 bf0 = *(const s16x8*)(wbase + i_ * 1024);                            \
      s16x8 bf1 = *(const s16x8*)(wbase + i_ * 1024 + 512);                      \
      acc0 = __builtin_amdgcn_mfma_f32_16x16x32_bf16(R[j], bf0, acc0, 0, 0, 0);  \
      acc1 = __builtin_amdgcn_mfma_f32_16x16x32_bf16(R[j], bf1, acc1, 0, 0, 0);  \
    }                                                                            \
  } while (0)

template <int XBF, int HIST>
__global__ __launch_bounds__(256, 1)
void lstm_persist(const short* __restrict__ Wp, const float* __restrict__ b_ih,
                  const float* __restrict__ b_hh, const float* __restrict__ cx,
                  const short* __restrict__ Xp, const float* __restrict__ xf32,
                  short* __restrict__ h0buf, short* __restrict__ h1buf,
                  short* __restrict__ hist0, short* __restrict__ hist1,
                  float* __restrict__ out, unsigned* bar)
{
  extern __shared__ char lds_raw[];
  short* wl = (short*)lds_raw;                              // 128 KB weight slice
  float (*gbuf)[33] = (float (*)[33])(lds_raw + WLDS_BYTES);

  const int blk = blockIdx.x;
  const int layer = blk >> 7;
  const int nblk = blk & 127;
  const int tid = threadIdx.x;
  const int lane = tid & 63;
  const int wave = tid >> 6;
  const int quad = lane >> 4;
  const int lo = lane & 15;
  const int n0 = nblk * 8;
  const int b = wave * 16 + lo;   // A-row = batch
  const int grp = blk >> 4;       // 16 barrier groups of 16 blocks

  // One-time weight stage (Wp layout == wave-read order; linear copy).
  {
    const s16x8* src = (const s16x8*)(Wp + ((long)blk << 16));
    s16x8* dst = (s16x8*)wl;
    for (int i = tid; i < 8192; i += 256) dst[i] = src[i];
  }

  // Block-private state in registers: c (2 floats) + 8 bias sums per thread.
  const int p0 = tid * 2;
  const int bb = p0 >> 3;         // batch of this thread's epilogue slice
  const int nl = p0 & 7;
  const int n_a = n0 + nl, n_b = n_a + 1;
  float c_a = cx[(bb * 2 + layer) * H_ + n_a];
  float c_b = cx[(bb * 2 + layer) * H_ + n_b];
  const float* bia = b_ih + layer * G4;
  const float* bib = b_hh + layer * G4;
  const float bi_a = bia[n_a] + bib[n_a],             bi_b = bia[n_b] + bib[n_b];
  const float bf_a = bia[1024 + n_a] + bib[1024 + n_a], bf_b = bia[1024 + n_b] + bib[1024 + n_b];
  const float bg_a = bia[2048 + n_a] + bib[2048 + n_a], bg_b = bia[2048 + n_b] + bib[2048 + n_b];
  const float bo_a = bia[3072 + n_a] + bib[3072 + n_a], bo_b = bia[3072 + n_b] + bib[3072 + n_b];

  const short* wbase = wl + lane * 8;
  __syncthreads();   // weight stage done

  for (int s = 0; s <= T_; s++) {
    const int active = (layer == 0) ? (s < T_) : (s > 0);
    if (active) {
      const int t = (layer == 0) ? s : (s - 1);
      const long sl = (long)s * 65536;           // fresh slice per step (HIST)
      const short* pAxl = nullptr;
      const short* pAhl;
      const float* xrow_f = nullptr;
      if (layer == 0) {
        if (XBF) pAxl = Xp + (long)t * 65536 + b * 8 + quad * 512;
        else     xrow_f = xf32 + ((long)b * T_ + t) * H_ + quad * 8;
        pAhl = (HIST ? hist0 + sl : h0buf + ((s + 1) & 1) * 65536) + b * 8 + quad * 512;
      } else {
        pAxl = (HIST ? hist0 + sl : h0buf + ((s + 1) & 1) * 65536) + b * 8 + quad * 512;
        pAhl = (HIST ? hist1 + sl : h1buf + (s & 1) * 65536) + b * 8 + quad * 512;
      }

      f32x4 acc0 = {0.f, 0.f, 0.f, 0.f}, acc1 = {0.f, 0.f, 0.f, 0.f};
      s16x8 ra[16], rb[16];   // two register banks, software-pipelined quarters

      LQX(ra, 0);
      LQX(rb, 1);
      COMPQ(ra, 0);
      LQH(ra, 0);
      COMPQ(rb, 1);
      LQH(rb, 1);
      COMPQ(ra, 2);
      COMPQ(rb, 3);

      // C/D layout: row(m) = quad*4 + reg, col(n) = lo  [verified m89/m91]
#pragma unroll
      for (int r = 0; r < 4; r++) {
        int m = wave * 16 + quad * 4 + r;
        gbuf[m][lo] = acc0[r];
        gbuf[m][16 + lo] = acc1[r];
      }
      __syncthreads();

      // gates for (bb, n_a) and (bb, n_b); c stays in registers
      float ig_a = gbuf[bb][nl]          + bi_a, ig_b = gbuf[bb][nl + 1]      + bi_b;
      float fg_a = gbuf[bb][8 + nl]      + bf_a, fg_b = gbuf[bb][8 + nl + 1]  + bf_b;
      float gg_a = gbuf[bb][16 + nl]     + bg_a, gg_b = gbuf[bb][16 + nl + 1] + bg_b;
      float og_a = gbuf[bb][24 + nl]     + bo_a, og_b = gbuf[bb][24 + nl + 1] + bo_b;
      c_a = fast_sigmoid(fg_a) * c_a + fast_sigmoid(ig_a) * fast_tanh(gg_a);
      c_b = fast_sigmoid(fg_b) * c_b + fast_sigmoid(ig_b) * fast_tanh(gg_b);
      float hn_a = fast_sigmoid(og_a) * fast_tanh(c_a);
      float hn_b = fast_sigmoid(og_b) * fast_tanh(c_b);

      short* hdst;
      if (HIST) hdst = (layer ? hist1 : hist0) + (long)(s + 1) * 65536 + nblk * 512;
      else      hdst = (layer ? h1buf : h0buf) + ((layer ? (s + 1) : s) & 1) * 65536 + nblk * 512;
      unsigned hp = (unsigned)(unsigned short)f2bf(hn_a)
                  | ((unsigned)(unsigned short)f2bf(hn_b) << 16);
      // Write-through to MALL: visible to next step's first-touch/coherent loads.
      __hip_atomic_store((unsigned*)(hdst + p0), hp, __ATOMIC_RELAXED, __HIP_MEMORY_SCOPE_AGENT);

      if (layer) {
        long oi = ((long)bb * T_ + t) * H_ + n_a;
        f32x2 o2 = {hn_a, hn_b};
        __builtin_nontemporal_store(o2, (f32x2*)(out + oi));  // keep L2 clean
        if (t == T_ - 1) {
          out[33554432L + bb * H_ + n_a] = hn_a;
          out[33554432L + bb * H_ + n_b] = hn_b;
          out[33554432L + 65536 + bb * H_ + n_a] = c_a;
          out[33554432L + 65536 + bb * H_ + n_b] = c_b;
        }
      }
    }

    // hierarchical monotonic barrier (no fences, no resets):
    // __syncthreads drains vmcnt (incl. the coherent h stores) before arrival.
    if (s < T_) {
      __syncthreads();
      if (tid == 0) {
        unsigned old = __hip_atomic_fetch_add(&bar[grp * 32], 1u,
                                              __ATOMIC_RELAXED, __HIP_MEMORY_SCOPE_AGENT);
        if (old == (unsigned)(s * 16 + 15))   // group-last of this step
          __hip_atomic_fetch_add(&bar[512], 1u,
                                 __ATOMIC_RELAXED, __HIP_MEMORY_SCOPE_AGENT);
        const unsigned target = (unsigned)((s + 1) * 16);
        int tries = 0;
        while (__hip_atomic_load(&bar[512], __ATOMIC_RELAXED, __HIP_MEMORY_SCOPE_AGENT) < target) {
          __builtin_amdgcn_s_sleep(2);
          if (++tries > (1 << 20)) break;   // clean-fail valve, no hang
        }
      }
      __syncthreads();
    }
  }
}

// ---- fallback path (proven per-step kernels), used only if cooperative launch errors ----
template <int XBF>
__global__ __launch_bounds__(256)
void lstm_step(const short* __restrict__ Wp, const float* __restrict__ bias,
               const short* __restrict__ Xp, const float* __restrict__ xf32,
               short* __restrict__ h0buf, short* __restrict__ h1buf,
               float* __restrict__ c0, float* __restrict__ c1,
               float* __restrict__ out, int s)
{
  const int blk = blockIdx.x;
  const int layer = blk >> 7;
  const int nblk = blk & 127;
  if (layer == 0 && s == T_) return;
  if (layer == 1 && s == 0) return;
  const int t = (layer == 0) ? s : (s - 1);

  const int lane = threadIdx.x & 63;
  const int wave = threadIdx.x >> 6;
  const int quad = lane >> 4;
  const int lo = lane & 15;
  const int n0 = nblk * 8;
  const int b = wave * 16 + lo;

  const short* baseX;
  const short* baseH;
  const float* xrow_f = nullptr;
  if (layer == 0) {
    baseX = Xp + (long)t * 65536;
    if (!XBF) xrow_f = xf32 + ((long)b * T_ + t) * H_;
    baseH = h0buf + ((s + 1) & 1) * 65536;
  } else {
    baseX = h0buf + ((s + 1) & 1) * 65536;
    baseH = h1buf + (s & 1) * 65536;
  }
  const short* pAx = baseX + b * 8;
  const short* pAh = baseH + b * 8;
  const short* wbase = Wp + ((long)(layer * 128 + nblk) << 16) + lane * 8;

  f32x4 acc0 = {0.f, 0.f, 0.f, 0.f}, acc1 = {0.f, 0.f, 0.f, 0.f};

#pragma unroll 4
  for (int k0 = 0; k0 < K2; k0 += 32) {
    const int koff = k0 + quad * 8;
    s16x8 af;
    if (koff < H_) {
      if (XBF || layer == 1) {
        af = *(const s16x8*)(pAx + koff * 64);
      } else {
        const float* p = xrow_f + koff;
        s16x8 tmp;
#pragma unroll
        for (int e = 0; e < 8; e++) tmp[e] = f2bf(p[e]);
        af = tmp;
      }
    } else {
      af = *(const s16x8*)(pAh + (koff - H_) * 64);
    }
    const s16x8 bf0 = *(const s16x8*)(wbase + k0 * 32);
    const s16x8 bf1 = *(const s16x8*)(wbase + k0 * 32 + 512);
    acc0 = __builtin_amdgcn_mfma_f32_16x16x32_bf16(af, bf0, acc0, 0, 0, 0);
    acc1 = __builtin_amdgcn_mfma_f32_16x16x32_bf16(af, bf1, acc1, 0, 0, 0);
  }

  __shared__ float gbuf[64][33];
#pragma unroll
  for (int r = 0; r < 4; r++) {
    int m = wave * 16 + quad * 4 + r;
    gbuf[m][lo] = acc0[r];
    gbuf[m][16 + lo] = acc1[r];
  }
  __syncthreads();

  float* cb = (layer ? c1 : c0) + nblk * 512;
  short* hdst = (layer ? h1buf : h0buf) + ((layer ? (s + 1) : s) & 1) * 65536 + nblk * 512;
  const float* bl = bias + layer * G4;

  for (int p = threadIdx.x; p < 512; p += 256) {
    int bb = p >> 3, nl = p & 7;
    int nn = n0 + nl;
    float ig = gbuf[bb][nl]      + bl[nn];
    float fg = gbuf[bb][8 + nl]  + bl[1024 + nn];
    float gg = gbuf[bb][16 + nl] + bl[2048 + nn];
    float og = gbuf[bb][24 + nl] + bl[3072 + nn];
    float cp = cb[p];
    float si = fast_sigmoid(ig);
    float sf = fast_sigmoid(fg);
    float so = fast_sigmoid(og);
    float cn = sf * cp + si * fast_tanh(gg);
    float hn = so * fast_tanh(cn);
    cb[p] = cn;
    hdst[p] = f2bf(hn);
    if (layer) {
      out[((long)bb * T_ + t) * H_ + nn] = hn;
      if (t == T_ - 1) {
        out[33554432L + bb * H_ + nn] = hn;
        out[33554432L + 65536 + bb * H_ + nn] = cn;
      }
    }
  }
}

extern "C" void kernel_launch(void* const* d_in, const int* in_sizes, int n_in,
                              void* d_out, int out_size, void* d_ws, size_t ws_size,
                              hipStream_t stream)
{
  const float* input_ = (const float*)d_in[0];
  const float* hx   = (const float*)d_in[1];
  const float* cx   = (const float*)d_in[2];
  const float* W_ih = (const float*)d_in[3];
  const float* W_hh = (const float*)d_in[4];
  const float* b_ih = (const float*)d_in[5];
  const float* b_hh = (const float*)d_in[6];
  float* out = (float*)d_out;

  const size_t WPB = 33554432, BIASB = 32768, XPB = 67108864;
  const size_t HB = 262144, CB = 262144, BARB = 4096;
  const size_t HISTB = (size_t)HIST_SLICES * 65536 * 2;   // 67,371,008

  const size_t tier2 = WPB + BIASB + XPB + 2 * HB + 2 * CB + BARB;  // ~101.7 MB
  const size_t tier3 = tier2 + 2 * HISTB;                            // ~236.5 MB

  int use_xbf  = (ws_size >= tier2) ? 1 : 0;
  int use_hist = (ws_size >= tier3) ? 1 : 0;

  char* w = (char*)d_ws;
  size_t off = 0;
  short* Wp  = (short*)(w + off); off += WPB;
  float* bias = (float*)(w + off); off += BIASB;
  short* Xp = nullptr;
  if (use_xbf) { Xp = (short*)(w + off); off += XPB; }
  short* h0buf = (short*)(w + off); off += HB;
  short* h1buf = (short*)(w + off); off += HB;
  float* c0 = (float*)(w + off); off += CB;           // fallback only
  float* c1 = (float*)(w + off); off += CB;           // fallback only
  unsigned* bar = (unsigned*)(w + off); off += BARB;
  short* hist0 = nullptr;
  short* hist1 = nullptr;
  if (use_hist) {
    hist0 = (short*)(w + off); off += HISTB;
    hist1 = (short*)(w + off); off += HISTB;
  }

  hipLaunchKernelGGL(prep_kernel, dim3(4096), dim3(256), 0, stream,
                     input_, hx, cx, W_ih, W_hh, b_ih, b_hh,
                     Wp, bias, Xp, h0buf, h1buf, c0, c1, bar, hist0, hist1,
                     use_xbf, use_hist);

  auto f11 = &lstm_persist<1, 1>;
  auto f10 = &lstm_persist<1, 0>;
  auto f00 = &lstm_persist<0, 0>;
  static int attr_done = 0;
  if (!attr_done) {
    (void)hipFuncSetAttribute(reinterpret_cast<const void*>(f11),
                              hipFuncAttributeMaxDynamicSharedMemorySize, LDS_BYTES);
    (void)hipFuncSetAttribute(reinterpret_cast<const void*>(f10),
                              hipFuncAttributeMaxDynamicSharedMemorySize, LDS_BYTES);
    (void)hipFuncSetAttribute(reinterpret_cast<const void*>(f00),
                              hipFuncAttributeMaxDynamicSharedMemorySize, LDS_BYTES);
    attr_done = 1;
  }

  void* args[] = {(void*)&Wp, (void*)&b_ih, (void*)&b_hh, (void*)&cx,
                  (void*)&Xp, (void*)&input_, (void*)&h0buf, (void*)&h1buf,
                  (void*)&hist0, (void*)&hist1, (void*)&out, (void*)&bar};
  hipError_t ce;
  if (use_hist) {
    ce = hipLaunchCooperativeKernel(f11, dim3(NPERS), dim3(256), args,
                                    (unsigned)LDS_BYTES, stream);
  } else if (use_xbf) {
    ce = hipLaunchCooperativeKernel(f10, dim3(NPERS), dim3(256), args,
                                    (unsigned)LDS_BYTES, stream);
  } else {
    ce = hipLaunchCooperativeKernel(f00, dim3(NPERS), dim3(256), args,
                                    (unsigned)LDS_BYTES, stream);
  }
  if (ce != hipSuccess) {
    // fallback: proven per-step path
    if (use_xbf) {
      for (int s = 0; s <= T_; s++)
        hipLaunchKernelGGL((lstm_step<1>), dim3(256), dim3(256), 0, stream,
                           Wp, bias, Xp, input_, h0buf, h1buf, c0, c1, out, s);
    } else {
      for (int s = 0; s <= T_; s++)
        hipLaunchKernelGGL((lstm_step<0>), dim3(256), dim3(256), 0, stream,
                           Wp, bias, Xp, input_, h0buf, h1buf, c0, c1, out, s);
    }
  }
}

// Round 6
// 4328.453 us; speedup vs baseline: 2.5576x; 2.5576x over previous
//
#include <hip/hip_runtime.h>

typedef __attribute__((ext_vector_type(8))) short s16x8;
typedef __attribute__((ext_vector_type(4))) float f32x4;
typedef __attribute__((ext_vector_type(2))) float f32x2;

#define B_ 64
#define T_ 512
#define H_ 1024
#define G4 4096      // 4*H
#define K2 2048      // D + H (fused input+recurrent K)
#define NPERS 256    // persistent grid = 1 block per CU
#define WLDS_BYTES 131072
#define LDS_BYTES (WLDS_BYTES + 64 * 33 * 4)   // weights + gbuf = 139520 B <= 160 KiB
#define HIST_SLICES 514                        // slices of 65536 shorts (128 KB) each

__device__ __forceinline__ short f2bf(float f) {
  union { float f; unsigned u; } x; x.f = f;
  unsigned r = (x.u + 0x7fffu + ((x.u >> 16) & 1u)) >> 16;  // RNE
  return (short)r;
}

__device__ __forceinline__ float fast_sigmoid(float x) {
  return 1.f / (1.f + __expf(-x));
}
__device__ __forceinline__ float fast_tanh(float x) {
  float e = __expf(-2.f * fabsf(x));          // overflow-safe
  float t = (1.f - e) / (1.f + e);
  return copysignf(t, x);
}

// MALL-coherent 16B load as two 8B relaxed agent-scope atomic loads (bypasses the
// non-coherent per-XCD L2). Used only in the non-HIST (address-reusing) mode.
__device__ __forceinline__ s16x8 cohload(const short* p) {
  union { unsigned long long u[2]; s16x8 v; } x;
  unsigned long long* q = (unsigned long long*)p;
  x.u[0] = __hip_atomic_load(q,     __ATOMIC_RELAXED, __HIP_MEMORY_SCOPE_AGENT);
  x.u[1] = __hip_atomic_load(q + 1, __ATOMIC_RELAXED, __HIP_MEMORY_SCOPE_AGENT);
  return x.v;
}

// Prep (one grid-stride kernel, ws re-poisoned 0xAA each call so rebuild everything):
//  Wp   [L][128 nblk][64 iter][2 frag][64 lane][8]  bf16  — exact wave-read order (coalesced B)
//  Xp   [T][128 chunk][64 b][8]                     bf16  — A-fragment chunked layout for x
//  h0/h1 [2 parity][128 chunk][64 b][8]             bf16  — fallback/non-HIST exchange bufs
//  hist0/hist1 [514 slice][128 chunk][64 b][8]      bf16  — HIST mode: never-reused slices
//  c0/c1, bias — only used by the (non-cooperative) fallback path
//  bar  [1024] u32 — hierarchical monotonic barrier: group g at bar[g*32], root at bar[512]
__global__ void prep_kernel(const float* __restrict__ input_, const float* __restrict__ hx,
                            const float* __restrict__ cx, const float* __restrict__ W_ih,
                            const float* __restrict__ W_hh, const float* __restrict__ b_ih,
                            const float* __restrict__ b_hh,
                            short* __restrict__ Wp, float* __restrict__ bias,
                            short* __restrict__ Xp, short* __restrict__ h0buf,
                            short* __restrict__ h1buf, float* __restrict__ c0,
                            float* __restrict__ c1, unsigned* __restrict__ bar,
                            short* __restrict__ hist0, short* __restrict__ hist1,
                            int use_xbf, int use_hist)
{
  const long total = use_xbf ? 33554432L : 16777216L;
  for (long idx = (long)blockIdx.x * blockDim.x + threadIdx.x; idx < total;
       idx += (long)gridDim.x * blockDim.x) {
    if (use_xbf && idx < 33554432L) {
      int e = idx & 7;
      int b = (idx >> 3) & 63;
      long tc = idx >> 9;
      int c = (int)(tc & 127);
      int t = (int)(tc >> 7);
      Xp[idx] = f2bf(input_[((long)b * T_ + t) * H_ + c * 8 + e]);
    }
    if (idx < 16777216L) {
      int lb = (int)(idx >> 16);            // layer*128+nblk
      int layer = lb >> 7, nblk = lb & 127;
      int r = (int)(idx & 65535);
      int e = r & 7;
      int lane = (r >> 3) & 63;
      int fragiter = r >> 9;
      int frag = fragiter & 1, iter = fragiter >> 1;
      int n = frag * 16 + (lane & 15);
      int k = iter * 32 + (lane >> 4) * 8 + e;
      int j = (n >> 3) * H_ + nblk * 8 + (n & 7);   // gate row (i,f,g,o grouped per block)
      float v = (k < H_) ? W_ih[((long)(layer << 12) + j) * H_ + k]
                         : W_hh[((long)(layer << 12) + j) * H_ + (k - H_)];
      Wp[idx] = f2bf(v);
    }
    if (idx < 8192) bias[idx] = b_ih[idx] + b_hh[idx];
    if (idx < 65536) {
      int b = (int)(idx >> 10), n = (int)(idx & 1023);
      int pi = (n >> 3) * 512 + b * 8 + (n & 7);    // chunked layout
      short i0 = f2bf(hx[(b * 2 + 0) * H_ + n]);
      short i1 = f2bf(hx[(b * 2 + 1) * H_ + n]);
      h0buf[65536 + pi] = i0;   // parity-1 initial state (non-HIST / fallback)
      h1buf[65536 + pi] = i1;
      if (use_hist) {
        hist0[pi] = i0;             // slice 0: read by layer0 at s=0
        hist1[65536 + pi] = i1;     // slice 1: read by layer1 at s=1
      }
      c0[pi] = cx[(b * 2 + 0) * H_ + n];
      c1[pi] = cx[(b * 2 + 1) * H_ + n];
    }
    if (idx < 1024) bar[idx] = 0u;
  }
}

// ---- persistent cooperative kernel ----
// 256 blocks (1/CU pinned by 136 KB LDS). Weights in LDS once. c-state + bias in
// registers. HIST mode: h exchanged via never-reused history slices — producers
// write-through to MALL (agent atomic stores), consumers use PLAIN loads (first
// touch per address → L2 miss, MSHR-merged across the 32 blocks/XCD → ~1 MALL
// fetch per line per XCD). sched_barrier(0) pins the load/compute interleave so
// the MI scheduler cannot sink the A-loads into the MFMA loop (round-4 lesson:
// VGPR 132→48 = banks deleted, pipeline destroyed).

#define UNR16 _Pragma("unroll") for (int j = 0; j < 16; j++)
#define SB __builtin_amdgcn_sched_barrier(0)

#define LQX(R, Q)                                                                \
  do {                                                                           \
    if (layer == 0) {                                                            \
      if (XBF) {                                                                 \
        UNR16 R[j] = *(const s16x8*)(pAxl + ((Q) * 16 + j) * 2048);              \
      } else {                                                                   \
        UNR16 {                                                                  \
          const float* pp = xrow_f + ((Q) * 16 + j) * 32;                        \
          s16x8 tmp;                                                             \
          _Pragma("unroll") for (int e = 0; e < 8; e++) tmp[e] = f2bf(pp[e]);    \
          R[j] = tmp;                                                            \
        }                                                                        \
      }                                                                          \
    } else {                                                                     \
      if (HIST) { UNR16 R[j] = *(const s16x8*)(pAxl + ((Q) * 16 + j) * 2048); }  \
      else      { UNR16 R[j] = cohload(pAxl + ((Q) * 16 + j) * 2048); }          \
    }                                                                            \
  } while (0)

#define LQH(R, Q2)                                                               \
  do {                                                                           \
    if (HIST) { UNR16 R[j] = *(const s16x8*)(pAhl + ((Q2) * 16 + j) * 2048); }   \
    else      { UNR16 R[j] = cohload(pAhl + ((Q2) * 16 + j) * 2048); }           \
  } while (0)

#define COMPQ(R, Q)                                                              \
  do {                                                                           \
    _Pragma("unroll") for (int j = 0; j < 16; j++) {                             \
      const int i_ = (Q) * 16 + j;                                               \
      s16x8 bf0 = *(const s16x8*)(wbase + i_ * 1024);                            \
      s16x8 bf1 = *(const s16x8*)(wbase + i_ * 1024 + 512);                      \
      acc0 = __builtin_amdgcn_mfma_f32_16x16x32_bf16(R[j], bf0, acc0, 0, 0, 0);  \
      acc1 = __builtin_amdgcn_mfma_f32_16x16x32_bf16(R[j], bf1, acc1, 0, 0, 0);  \
    }                                                                            \
  } while (0)

template <int XBF, int HIST>
__global__ __launch_bounds__(256, 1)
void lstm_persist(const short* __restrict__ Wp, const float* __restrict__ b_ih,
                  const float* __restrict__ b_hh, const float* __restrict__ cx,
                  const short* __restrict__ Xp, const float* __restrict__ xf32,
                  short* __restrict__ h0buf, short* __restrict__ h1buf,
                  short* __restrict__ hist0, short* __restrict__ hist1,
                  float* __restrict__ out, unsigned* bar)
{
  extern __shared__ char lds_raw[];
  short* wl = (short*)lds_raw;                              // 128 KB weight slice
  float (*gbuf)[33] = (float (*)[33])(lds_raw + WLDS_BYTES);

  const int blk = blockIdx.x;
  const int layer = blk >> 7;
  const int nblk = blk & 127;
  const int tid = threadIdx.x;
  const int lane = tid & 63;
  const int wave = tid >> 6;
  const int quad = lane >> 4;
  const int lo = lane & 15;
  const int n0 = nblk * 8;
  const int b = wave * 16 + lo;   // A-row = batch
  const int grp = blk >> 4;       // 16 barrier groups of 16 blocks

  // One-time weight stage (Wp layout == wave-read order; linear copy).
  {
    const s16x8* src = (const s16x8*)(Wp + ((long)blk << 16));
    s16x8* dst = (s16x8*)wl;
    for (int i = tid; i < 8192; i += 256) dst[i] = src[i];
  }

  // Block-private state in registers: c (2 floats) + 8 bias sums per thread.
  const int p0 = tid * 2;
  const int bb = p0 >> 3;         // batch of this thread's epilogue slice
  const int nl = p0 & 7;
  const int n_a = n0 + nl, n_b = n_a + 1;
  float c_a = cx[(bb * 2 + layer) * H_ + n_a];
  float c_b = cx[(bb * 2 + layer) * H_ + n_b];
  const float* bia = b_ih + layer * G4;
  const float* bib = b_hh + layer * G4;
  const float bi_a = bia[n_a] + bib[n_a],             bi_b = bia[n_b] + bib[n_b];
  const float bf_a = bia[1024 + n_a] + bib[1024 + n_a], bf_b = bia[1024 + n_b] + bib[1024 + n_b];
  const float bg_a = bia[2048 + n_a] + bib[2048 + n_a], bg_b = bia[2048 + n_b] + bib[2048 + n_b];
  const float bo_a = bia[3072 + n_a] + bib[3072 + n_a], bo_b = bia[3072 + n_b] + bib[3072 + n_b];

  const short* wbase = wl + lane * 8;
  __syncthreads();   // weight stage done

  for (int s = 0; s <= T_; s++) {
    const int active = (layer == 0) ? (s < T_) : (s > 0);
    if (active) {
      const int t = (layer == 0) ? s : (s - 1);
      const long sl = (long)s * 65536;           // fresh slice per step (HIST)
      const short* pAxl = nullptr;
      const short* pAhl;
      const float* xrow_f = nullptr;
      if (layer == 0) {
        if (XBF) pAxl = Xp + (long)t * 65536 + b * 8 + quad * 512;
        else     xrow_f = xf32 + ((long)b * T_ + t) * H_ + quad * 8;
        pAhl = (HIST ? hist0 + sl : h0buf + ((s + 1) & 1) * 65536) + b * 8 + quad * 512;
      } else {
        pAxl = (HIST ? hist0 + sl : h0buf + ((s + 1) & 1) * 65536) + b * 8 + quad * 512;
        pAhl = (HIST ? hist1 + sl : h1buf + (s & 1) * 65536) + b * 8 + quad * 512;
      }

      f32x4 acc0 = {0.f, 0.f, 0.f, 0.f}, acc1 = {0.f, 0.f, 0.f, 0.f};
      s16x8 ra[16], rb[16];   // two register banks, software-pipelined quarters

      // Pinned schedule (round-3 structure): loads for quarter q+1 in flight
      // while quarter q computes. SB = sched_barrier(0) stops load sinking.
      LQX(ra, 0); SB;
      LQX(rb, 1); SB;
      COMPQ(ra, 0); SB;
      LQH(ra, 0); SB;
      COMPQ(rb, 1); SB;
      LQH(rb, 1); SB;
      COMPQ(ra, 2); SB;
      COMPQ(rb, 3);

      // C/D layout: row(m) = quad*4 + reg, col(n) = lo  [verified m89/m91]
#pragma unroll
      for (int r = 0; r < 4; r++) {
        int m = wave * 16 + quad * 4 + r;
        gbuf[m][lo] = acc0[r];
        gbuf[m][16 + lo] = acc1[r];
      }
      __syncthreads();

      // gates for (bb, n_a) and (bb, n_b); c stays in registers
      float ig_a = gbuf[bb][nl]          + bi_a, ig_b = gbuf[bb][nl + 1]      + bi_b;
      float fg_a = gbuf[bb][8 + nl]      + bf_a, fg_b = gbuf[bb][8 + nl + 1]  + bf_b;
      float gg_a = gbuf[bb][16 + nl]     + bg_a, gg_b = gbuf[bb][16 + nl + 1] + bg_b;
      float og_a = gbuf[bb][24 + nl]     + bo_a, og_b = gbuf[bb][24 + nl + 1] + bo_b;
      c_a = fast_sigmoid(fg_a) * c_a + fast_sigmoid(ig_a) * fast_tanh(gg_a);
      c_b = fast_sigmoid(fg_b) * c_b + fast_sigmoid(ig_b) * fast_tanh(gg_b);
      float hn_a = fast_sigmoid(og_a) * fast_tanh(c_a);
      float hn_b = fast_sigmoid(og_b) * fast_tanh(c_b);

      short* hdst;
      if (HIST) hdst = (layer ? hist1 : hist0) + (long)(s + 1) * 65536 + nblk * 512;
      else      hdst = (layer ? h1buf : h0buf) + ((layer ? (s + 1) : s) & 1) * 65536 + nblk * 512;
      unsigned hp = (unsigned)(unsigned short)f2bf(hn_a)
                  | ((unsigned)(unsigned short)f2bf(hn_b) << 16);
      // Write-through to MALL: visible to next step's first-touch/coherent loads.
      __hip_atomic_store((unsigned*)(hdst + p0), hp, __ATOMIC_RELAXED, __HIP_MEMORY_SCOPE_AGENT);

      if (layer) {
        long oi = ((long)bb * T_ + t) * H_ + n_a;
        f32x2 o2 = {hn_a, hn_b};
        __builtin_nontemporal_store(o2, (f32x2*)(out + oi));  // keep L2 clean
        if (t == T_ - 1) {
          out[33554432L + bb * H_ + n_a] = hn_a;
          out[33554432L + bb * H_ + n_b] = hn_b;
          out[33554432L + 65536 + bb * H_ + n_a] = c_a;
          out[33554432L + 65536 + bb * H_ + n_b] = c_b;
        }
      }
    }

    // hierarchical monotonic barrier (no fences, no resets):
    // __syncthreads drains vmcnt (incl. the coherent h stores) before arrival.
    if (s < T_) {
      __syncthreads();
      if (tid == 0) {
        unsigned old = __hip_atomic_fetch_add(&bar[grp * 32], 1u,
                                              __ATOMIC_RELAXED, __HIP_MEMORY_SCOPE_AGENT);
        if (old == (unsigned)(s * 16 + 15))   // group-last of this step
          __hip_atomic_fetch_add(&bar[512], 1u,
                                 __ATOMIC_RELAXED, __HIP_MEMORY_SCOPE_AGENT);
        const unsigned target = (unsigned)((s + 1) * 16);
        int tries = 0;
        while (__hip_atomic_load(&bar[512], __ATOMIC_RELAXED, __HIP_MEMORY_SCOPE_AGENT) < target) {
          __builtin_amdgcn_s_sleep(2);
          if (++tries > (1 << 18)) break;   // clean-fail valve, no hang (~30ms cap)
        }
      }
      __syncthreads();
    }
  }
}

// ---- fallback path (proven per-step kernels), used only if cooperative launch errors ----
template <int XBF>
__global__ __launch_bounds__(256)
void lstm_step(const short* __restrict__ Wp, const float* __restrict__ bias,
               const short* __restrict__ Xp, const float* __restrict__ xf32,
               short* __restrict__ h0buf, short* __restrict__ h1buf,
               float* __restrict__ c0, float* __restrict__ c1,
               float* __restrict__ out, int s)
{
  const int blk = blockIdx.x;
  const int layer = blk >> 7;
  const int nblk = blk & 127;
  if (layer == 0 && s == T_) return;
  if (layer == 1 && s == 0) return;
  const int t = (layer == 0) ? s : (s - 1);

  const int lane = threadIdx.x & 63;
  const int wave = threadIdx.x >> 6;
  const int quad = lane >> 4;
  const int lo = lane & 15;
  const int n0 = nblk * 8;
  const int b = wave * 16 + lo;

  const short* baseX;
  const short* baseH;
  const float* xrow_f = nullptr;
  if (layer == 0) {
    baseX = Xp + (long)t * 65536;
    if (!XBF) xrow_f = xf32 + ((long)b * T_ + t) * H_;
    baseH = h0buf + ((s + 1) & 1) * 65536;
  } else {
    baseX = h0buf + ((s + 1) & 1) * 65536;
    baseH = h1buf + (s & 1) * 65536;
  }
  const short* pAx = baseX + b * 8;
  const short* pAh = baseH + b * 8;
  const short* wbase = Wp + ((long)(layer * 128 + nblk) << 16) + lane * 8;

  f32x4 acc0 = {0.f, 0.f, 0.f, 0.f}, acc1 = {0.f, 0.f, 0.f, 0.f};

#pragma unroll 4
  for (int k0 = 0; k0 < K2; k0 += 32) {
    const int koff = k0 + quad * 8;
    s16x8 af;
    if (koff < H_) {
      if (XBF || layer == 1) {
        af = *(const s16x8*)(pAx + koff * 64);
      } else {
        const float* p = xrow_f + koff;
        s16x8 tmp;
#pragma unroll
        for (int e = 0; e < 8; e++) tmp[e] = f2bf(p[e]);
        af = tmp;
      }
    } else {
      af = *(const s16x8*)(pAh + (koff - H_) * 64);
    }
    const s16x8 bf0 = *(const s16x8*)(wbase + k0 * 32);
    const s16x8 bf1 = *(const s16x8*)(wbase + k0 * 32 + 512);
    acc0 = __builtin_amdgcn_mfma_f32_16x16x32_bf16(af, bf0, acc0, 0, 0, 0);
    acc1 = __builtin_amdgcn_mfma_f32_16x16x32_bf16(af, bf1, acc1, 0, 0, 0);
  }

  __shared__ float gbuf[64][33];
#pragma unroll
  for (int r = 0; r < 4; r++) {
    int m = wave * 16 + quad * 4 + r;
    gbuf[m][lo] = acc0[r];
    gbuf[m][16 + lo] = acc1[r];
  }
  __syncthreads();

  float* cb = (layer ? c1 : c0) + nblk * 512;
  short* hdst = (layer ? h1buf : h0buf) + ((layer ? (s + 1) : s) & 1) * 65536 + nblk * 512;
  const float* bl = bias + layer * G4;

  for (int p = threadIdx.x; p < 512; p += 256) {
    int bb = p >> 3, nl = p & 7;
    int nn = n0 + nl;
    float ig = gbuf[bb][nl]      + bl[nn];
    float fg = gbuf[bb][8 + nl]  + bl[1024 + nn];
    float gg = gbuf[bb][16 + nl] + bl[2048 + nn];
    float og = gbuf[bb][24 + nl] + bl[3072 + nn];
    float cp = cb[p];
    float si = fast_sigmoid(ig);
    float sf = fast_sigmoid(fg);
    float so = fast_sigmoid(og);
    float cn = sf * cp + si * fast_tanh(gg);
    float hn = so * fast_tanh(cn);
    cb[p] = cn;
    hdst[p] = f2bf(hn);
    if (layer) {
      out[((long)bb * T_ + t) * H_ + nn] = hn;
      if (t == T_ - 1) {
        out[33554432L + bb * H_ + nn] = hn;
        out[33554432L + 65536 + bb * H_ + nn] = cn;
      }
    }
  }
}

extern "C" void kernel_launch(void* const* d_in, const int* in_sizes, int n_in,
                              void* d_out, int out_size, void* d_ws, size_t ws_size,
                              hipStream_t stream)
{
  const float* input_ = (const float*)d_in[0];
  const float* hx   = (const float*)d_in[1];
  const float* cx   = (const float*)d_in[2];
  const float* W_ih = (const float*)d_in[3];
  const float* W_hh = (const float*)d_in[4];
  const float* b_ih = (const float*)d_in[5];
  const float* b_hh = (const float*)d_in[6];
  float* out = (float*)d_out;

  const size_t WPB = 33554432, BIASB = 32768, XPB = 67108864;
  const size_t HB = 262144, CB = 262144, BARB = 4096;
  const size_t HISTB = (size_t)HIST_SLICES * 65536 * 2;   // 67,371,008

  const size_t tier2 = WPB + BIASB + XPB + 2 * HB + 2 * CB + BARB;  // ~101.7 MB
  const size_t tier3 = tier2 + 2 * HISTB;                            // ~236.5 MB

  int use_xbf  = (ws_size >= tier2) ? 1 : 0;
  int use_hist = (ws_size >= tier3) ? 1 : 0;

  char* w = (char*)d_ws;
  size_t off = 0;
  short* Wp  = (short*)(w + off); off += WPB;
  float* bias = (float*)(w + off); off += BIASB;
  short* Xp = nullptr;
  if (use_xbf) { Xp = (short*)(w + off); off += XPB; }
  short* h0buf = (short*)(w + off); off += HB;
  short* h1buf = (short*)(w + off); off += HB;
  float* c0 = (float*)(w + off); off += CB;           // fallback only
  float* c1 = (float*)(w + off); off += CB;           // fallback only
  unsigned* bar = (unsigned*)(w + off); off += BARB;
  short* hist0 = nullptr;
  short* hist1 = nullptr;
  if (use_hist) {
    hist0 = (short*)(w + off); off += HISTB;
    hist1 = (short*)(w + off); off += HISTB;
  }

  hipLaunchKernelGGL(prep_kernel, dim3(4096), dim3(256), 0, stream,
                     input_, hx, cx, W_ih, W_hh, b_ih, b_hh,
                     Wp, bias, Xp, h0buf, h1buf, c0, c1, bar, hist0, hist1,
                     use_xbf, use_hist);

  auto f11 = &lstm_persist<1, 1>;
  auto f10 = &lstm_persist<1, 0>;
  auto f00 = &lstm_persist<0, 0>;
  static int attr_done = 0;
  if (!attr_done) {
    (void)hipFuncSetAttribute(reinterpret_cast<const void*>(f11),
                              hipFuncAttributeMaxDynamicSharedMemorySize, LDS_BYTES);
    (void)hipFuncSetAttribute(reinterpret_cast<const void*>(f10),
                              hipFuncAttributeMaxDynamicSharedMemorySize, LDS_BYTES);
    (void)hipFuncSetAttribute(reinterpret_cast<const void*>(f00),
                              hipFuncAttributeMaxDynamicSharedMemorySize, LDS_BYTES);
    attr_done = 1;
  }

  void* args[] = {(void*)&Wp, (void*)&b_ih, (void*)&b_hh, (void*)&cx,
                  (void*)&Xp, (void*)&input_, (void*)&h0buf, (void*)&h1buf,
                  (void*)&hist0, (void*)&hist1, (void*)&out, (void*)&bar};
  hipError_t ce;
  if (use_hist) {
    ce = hipLaunchCooperativeKernel(f11, dim3(NPERS), dim3(256), args,
                                    (unsigned)LDS_BYTES, stream);
  } else if (use_xbf) {
    ce = hipLaunchCooperativeKernel(f10, dim3(NPERS), dim3(256), args,
                                    (unsigned)LDS_BYTES, stream);
  } else {
    ce = hipLaunchCooperativeKernel(f00, dim3(NPERS), dim3(256), args,
                                    (unsigned)LDS_BYTES, stream);
  }
  if (ce != hipSuccess) {
    // fallback: proven per-step path
    if (use_xbf) {
      for (int s = 0; s <= T_; s++)
        hipLaunchKernelGGL((lstm_step<1>), dim3(256), dim3(256), 0, stream,
                           Wp, bias, Xp, input_, h0buf, h1buf, c0, c1, out, s);
    } else {
      for (int s = 0; s <= T_; s++)
        hipLaunchKernelGGL((lstm_step<0>), dim3(256), dim3(256), 0, stream,
                           Wp, bias, Xp, input_, h0buf, h1buf, c0, c1, out, s);
    }
  }
}